// Round 9
// baseline (429.681 us; speedup 1.0000x reference)
//
#include <hip/hip_runtime.h>
#include <hip/hip_bf16.h>

#define B_    8
#define NP    2352
#define D_    512
#define SENT  48
#define PAIRS 512
#define NERL  16
#define REL   32
#define MTOT  (B_*NP)   // 18816

typedef unsigned short u16;
typedef __bf16 bf16x8 __attribute__((ext_vector_type(8)));
typedef float  f32x4  __attribute__((ext_vector_type(4)));

__device__ __forceinline__ u16 f2b(float f) {
  union { float f; unsigned u; } c; c.f = f;
  unsigned u = c.u;
  u += 0x7fffu + ((u >> 16) & 1u);           // round-to-nearest-even
  return (u16)(u >> 16);
}
__device__ __forceinline__ float b2f(u16 h) {
  union { unsigned u; float f; } c; c.u = ((unsigned)h) << 16;
  return c.f;
}
__device__ __forceinline__ void gload16(const u16* g, u16* lds) {
  __builtin_amdgcn_global_load_lds(
      (const __attribute__((address_space(1))) unsigned*)g,
      (__attribute__((address_space(3))) unsigned*)lds, 16, 0, 0);
}

// ----------------------------------------------------------------- zero ----
__global__ void zero_zp(u16* zp) { zp[threadIdx.x] = 0; }

// ------------------------------------------------------------- prep_adj ----
__global__ __launch_bounds__(256) void prep_adj(const float* __restrict__ adj,
                                                u16* __restrict__ adjb,
                                                float* __restrict__ rdenom) {
  const int row = blockIdx.x;                 // 0..18815
  const float4* src = (const float4*)(adj + (size_t)row * NP);
  ushort4* dst = (ushort4*)(adjb + (size_t)row * NP);
  float s = 0.f;
  for (int i = threadIdx.x; i < NP / 4; i += 256) {
    float4 v = src[i];
    s += (v.x + v.y) + (v.z + v.w);
    ushort4 o; o.x = f2b(v.x); o.y = f2b(v.y); o.z = f2b(v.z); o.w = f2b(v.w);
    dst[i] = o;
  }
  #pragma unroll
  for (int o = 32; o > 0; o >>= 1) s += __shfl_down(s, o, 64);
  __shared__ float red[4];
  int w = threadIdx.x >> 6, l = threadIdx.x & 63;
  if (l == 0) red[w] = s;
  __syncthreads();
  if (threadIdx.x == 0)
    rdenom[row] = 1.f / (red[0] + red[1] + red[2] + red[3] + 1.f);
}

// ----------------------------------------------------- transpose-convert ---
__global__ __launch_bounds__(256) void tcvt(const float* __restrict__ in_,
                                            u16* __restrict__ out,
                                            int R, int C, size_t inb, size_t outb) {
  __shared__ u16 tile[64][65];
  const int b  = blockIdx.z;
  const int r0 = blockIdx.x * 64, c0 = blockIdx.y * 64;
  const int t  = threadIdx.x;
  const int tr = t >> 4, tc = (t & 15) * 4;
  #pragma unroll
  for (int i = 0; i < 4; ++i) {
    int rl = i * 16 + tr;
    int r  = r0 + rl;
    if (r < R) {
      const float* in = in_ + (size_t)b * inb + (size_t)r * C + c0 + tc;
      float4 v = *(const float4*)in;
      tile[rl][tc + 0] = f2b(v.x); tile[rl][tc + 1] = f2b(v.y);
      tile[rl][tc + 2] = f2b(v.z); tile[rl][tc + 3] = f2b(v.w);
    }
  }
  __syncthreads();
  const int c  = t >> 2;
  const int rb = (t & 3) * 16;
  u16* orow = out + (size_t)b * outb + (size_t)(c0 + c) * R + r0;
  #pragma unroll
  for (int i = 0; i < 4; ++i) {
    int rl = rb + i * 4;
    int r  = r0 + rl;
    if (r + 3 < R) {
      ushort4 v;
      v.x = tile[rl + 0][c]; v.y = tile[rl + 1][c];
      v.z = tile[rl + 2][c]; v.w = tile[rl + 3][c];
      *(ushort4*)(orow + rl) = v;
    } else {
      for (int j = 0; j < 4; ++j)
        if (r + j < R) orow[rl + j] = tile[rl + j][c];
    }
  }
}

// --------------------------- dual-K-group 128x128 GEMM, 16 waves/CU --------
// 512 thr = 2 K-groups x 4 waves. Group g computes K-range [g*KSPL, ...),
// KG BK=32 steps each, own 16KB dbuf pair (64 KB LDS total -> 2 blocks/CU
// -> 16 waves/CU, 4 independent vmem streams/CU). Block barriers align the
// groups' identical step counts. Final f32 reduce via LDS (2 x 32KB rounds),
// epilogue by group 0. Swizzle slot = lq ^ ((row>>1)&3) both sides (0 conf).
// K-tail / range overrun -> zero page.
template<int MODE, int WRITE_T>
__global__ __launch_bounds__(512, 4) void gemm8(
    const u16* __restrict__ A, const u16* __restrict__ A2,
    const u16* __restrict__ Bm, const u16* __restrict__ Xt,
    const float* __restrict__ bias, const float* __restrict__ rdenom,
    const u16* __restrict__ zp, u16* __restrict__ out, u16* __restrict__ outT)
{
  constexpr int KACT = (MODE == 0) ? NP : (MODE == 1 ? 512 : 1024);
  constexpr int KG   = (MODE == 0) ? 37 : (MODE == 1 ? 8 : 16);  // steps/group
  constexpr int LDA  = (MODE == 0) ? NP : 512;
  constexpr int LDB  = KACT;

  int m0, n0;
  const u16* Ab = A;
  const u16* Bb = Bm;
  const u16* Xb = Xt;
  size_t outBase = 0;
  if constexpr (MODE == 0) {
    // grid 608 = 8 XCD chunks x 76 (one batch per chunk); 19 m x 4 n
    const int bx  = blockIdx.x;
    const int bat = bx & 7;
    const int loc = bx >> 3;                  // 0..75
    const int mt  = loc >> 2;                 // 0..18
    n0 = (loc & 3) << 7;
    m0 = (mt < 18) ? mt * 128 : NP - 128;     // overlap last tile
    Ab = A  + (size_t)bat * NP * NP;
    Bb = Bm + (size_t)bat * 512 * NP;
    Xb = Xt + (size_t)bat * 512 * NP;
    outBase = (size_t)bat * NP * 512;
  } else {
    // grid 588 = 147 m x 4 n; bijective XCD chunking (q=73, r=4)
    const int bx  = blockIdx.x;
    const int xcd = bx & 7, pos = bx >> 3;
    const int rid = (xcd < 4) ? xcd * 74 + pos : 296 + (xcd - 4) * 73 + pos;
    const int mt  = rid >> 2;                 // 0..146
    n0 = (rid & 3) << 7;
    m0 = mt * 128;                            // exact (147*128 = 18816)
  }

  // [group][dbuf][128 rows][4 slots x 8 u16]; u16 off = g*8192+d*4096+cl*8
  __shared__ __align__(16) u16 As[2 * 8192];   // 32 KB
  __shared__ __align__(16) u16 Bs[2 * 8192];   // 32 KB

  const int tid = threadIdx.x;
  const int g   = tid >> 8;          // K-group
  const int tl  = tid & 255;         // thread-in-group
  const int l   = tid & 63;
  const int w   = tl >> 6;           // wave-in-group 0..3
  const int wm = w >> 1, wn = w & 1;
  const int lr = l & 15, lq = l >> 4;
  const int KOFFCH = g * KG * 4;     // group-1 chunk offset

  f32x4 acc[4][4];
  #pragma unroll
  for (int i = 0; i < 4; ++i)
    #pragma unroll
    for (int j = 0; j < 4; ++j)
      acc[i][j] = (f32x4){0.f, 0.f, 0.f, 0.f};

  // Stage this group's A+B BK=32 slab of step kt into dbuf d. 4 loads/thread.
  auto STAGE = [&](int d, int kt) {
    #pragma unroll
    for (int j = 0; j < 2; ++j) {
      const int cl   = j * 256 + tl;           // 0..511
      const int row  = cl >> 2;                // 0..127
      const int slot = cl & 3;
      const int gch  = KOFFCH + kt * 4 + (slot ^ ((row >> 1) & 3));
      { // A
        const int gm = m0 + row;
        const u16* src;
        if constexpr (MODE == 2) {
          src = (gch < 64) ? A  + (size_t)gm * 512 + gch * 8
                           : A2 + (size_t)gm * 512 + (gch - 64) * 8;
        } else {
          src = Ab + (size_t)gm * LDA + gch * 8;
        }
        if (gch * 8 + 8 > KACT) src = zp;
        gload16(src, As + g * 8192 + d * 4096 + cl * 8);
      }
      { // B
        const u16* src = Bb + (size_t)(n0 + row) * LDB + gch * 8;
        if (gch * 8 + 8 > KACT) src = zp;
        gload16(src, Bs + g * 8192 + d * 4096 + cl * 8);
      }
    }
  };

  STAGE(0, 0);
  asm volatile("s_waitcnt vmcnt(0)" ::: "memory");
  __builtin_amdgcn_s_barrier();

  int d = 0;
  for (int kt = 0; kt < KG; ++kt) {
    if (kt + 1 < KG) STAGE(d ^ 1, kt + 1);     // overlap with this step
    const u16* Ad = As + g * 8192 + d * 4096;
    const u16* Bd = Bs + g * 8192 + d * 4096;
    bf16x8 af[4], bg[4];
    #pragma unroll
    for (int f = 0; f < 4; ++f) {
      const int ra = wm * 64 + f * 16 + lr;
      const int rb = wn * 64 + f * 16 + lr;
      af[f] = *(const bf16x8*)(Ad + ra * 32 + ((lq ^ ((ra >> 1) & 3)) << 3));
      bg[f] = *(const bf16x8*)(Bd + rb * 32 + ((lq ^ ((rb >> 1) & 3)) << 3));
    }
    asm volatile("s_waitcnt lgkmcnt(0)" ::: "memory");
    __builtin_amdgcn_sched_barrier(0);          // rule #18
    __builtin_amdgcn_s_setprio(1);
    #pragma unroll
    for (int mf = 0; mf < 4; ++mf)
      #pragma unroll
      for (int nf = 0; nf < 4; ++nf)
        acc[mf][nf] = __builtin_amdgcn_mfma_f32_16x16x32_bf16(
            af[mf], bg[nf], acc[mf][nf], 0, 0, 0);
    __builtin_amdgcn_s_setprio(0);
    __builtin_amdgcn_sched_barrier(0);
    asm volatile("s_waitcnt vmcnt(0)" ::: "memory");  // next slab landed
    __builtin_amdgcn_s_barrier();
    d ^= 1;
  }

  // ---- cross-group f32 reduction via LDS (2 rounds x 32 KB over As) ------
  float4* red = (float4*)As;
  #pragma unroll
  for (int r = 0; r < 2; ++r) {
    if (g == 1) {
      #pragma unroll
      for (int vc = 0; vc < 8; ++vc) {
        const int mf = r * 2 + (vc >> 2), nf = vc & 3;
        red[(vc * 4 + w) * 64 + l] =
            (float4){acc[mf][nf][0], acc[mf][nf][1], acc[mf][nf][2], acc[mf][nf][3]};
      }
    }
    __builtin_amdgcn_s_barrier();
    if (g == 0) {
      #pragma unroll
      for (int vc = 0; vc < 8; ++vc) {
        const int mf = r * 2 + (vc >> 2), nf = vc & 3;
        float4 v = red[(vc * 4 + w) * 64 + l];
        acc[mf][nf][0] += v.x; acc[mf][nf][1] += v.y;
        acc[mf][nf][2] += v.z; acc[mf][nf][3] += v.w;
      }
    }
    __builtin_amdgcn_s_barrier();
  }
  if (g != 0) return;

  // --------------------------------------------------------- epilogue ----
  #pragma unroll
  for (int mf = 0; mf < 4; ++mf) {
    const int gm0 = m0 + wm * 64 + mf * 16 + lq * 4;
    f32x4 rd;
    if constexpr (MODE == 1) rd = *(const f32x4*)(rdenom + gm0);
    #pragma unroll
    for (int nf = 0; nf < 4; ++nf) {
      const int gn = n0 + wn * 64 + nf * 16 + lr;
      u16 ov[4];
      if constexpr (MODE == 0) {
        ushort4 xv = *(const ushort4*)(Xb + (size_t)gn * NP + gm0);
        const float xf[4] = {b2f(xv.x), b2f(xv.y), b2f(xv.z), b2f(xv.w)};
        #pragma unroll
        for (int r = 0; r < 4; ++r) ov[r] = f2b(acc[mf][nf][r] + xf[r]);
      } else if constexpr (MODE == 1) {
        const float bn = 2.f * bias[gn];
        #pragma unroll
        for (int r = 0; r < 4; ++r)
          ov[r] = f2b(fmaxf((acc[mf][nf][r] + bn) * rd[r], 0.f));
      } else {
        const float bn = bias[gn];
        #pragma unroll
        for (int r = 0; r < 4; ++r) ov[r] = f2b(acc[mf][nf][r] + bn);
      }
      #pragma unroll
      for (int r = 0; r < 4; ++r)
        out[outBase + (size_t)(gm0 + r) * 512 + gn] = ov[r];
      if constexpr (WRITE_T) {
        const int bb = gm0 / NP;                 // quad never straddles batch
        const int ml = gm0 - bb * NP;
        ushort4 tv; tv.x = ov[0]; tv.y = ov[1]; tv.z = ov[2]; tv.w = ov[3];
        *(ushort4*)(outT + ((size_t)bb * 512 + gn) * NP + ml) = tv;
      }
    }
  }
}

// ------------------------------------------------------------- ner head ----
__global__ __launch_bounds__(64) void ner_kernel(const float* __restrict__ ner,
                                                 const u16* __restrict__ logits,
                                                 const float* __restrict__ nw,
                                                 const float* __restrict__ nb,
                                                 float* __restrict__ out) {
  int r = blockIdx.x;                 // 0..383
  int b = r / SENT, tp = r % SENT;
  int lane = threadIdx.x;
  const float* nrow = ner    + ((size_t)b * SENT + tp) * D_;
  const u16*   lrow = logits + ((size_t)b * NP   + tp) * D_;
  float rv[16];
  #pragma unroll
  for (int i = 0; i < 8; ++i) rv[i]     = nrow[lane + i * 64];
  #pragma unroll
  for (int i = 0; i < 8; ++i) rv[8 + i] = b2f(lrow[lane + i * 64]);
  for (int j = 0; j < NERL; ++j) {
    float s = 0.f;
    #pragma unroll
    for (int i = 0; i < 16; ++i)
      s = fmaf(rv[i], nw[(size_t)(lane + i * 64) * NERL + j], s);
    for (int o = 32; o > 0; o >>= 1) s += __shfl_down(s, o);
    if (lane == 0) out[r * NERL + j] = s + nb[j];
  }
}

// ----------------------------------------------------------- pair + re -----
__global__ __launch_bounds__(256) void pair_kernel(const u16* __restrict__ logits,
                                                   const float* __restrict__ refeat,
                                                   const float* __restrict__ rw,
                                                   const float* __restrict__ rb,
                                                   const int* __restrict__ ps,
                                                   const int* __restrict__ hs,
                                                   const int* __restrict__ ts,
                                                   float* __restrict__ out) {
  int p = blockIdx.x;
  __shared__ float avg[D_];
  int b = ps[p], h = hs[p], tt = ts[p];
  const u16* base = logits + (size_t)b * NP * D_;
  const u16* r00 = base + (size_t)((h + 1) * SENT + tt) * D_;
  const u16* r01 = base + (size_t)((h + 1) * SENT + tt + 1) * D_;
  const u16* r10 = base + (size_t)((h + 2) * SENT + tt) * D_;
  const u16* r11 = base + (size_t)((h + 2) * SENT + tt + 1) * D_;
  for (int dd = threadIdx.x; dd < D_; dd += 256)
    avg[dd] = 0.25f * (b2f(r00[dd]) + b2f(r01[dd]) + b2f(r10[dd]) + b2f(r11[dd]));
  __syncthreads();
  int wave = threadIdx.x >> 6, lane = threadIdx.x & 63;
  const float* rf = refeat + (size_t)p * D_;
  for (int jj = 0; jj < 8; ++jj) {
    int j = wave * 8 + jj;
    float s = 0.f;
    #pragma unroll
    for (int i = 0; i < 8; ++i) {
      int k = lane + i * 64;
      s = fmaf(rf[k],  rw[(size_t)k * REL + j], s);
      s = fmaf(avg[k], rw[(size_t)(k + D_) * REL + j], s);
    }
    for (int o = 32; o > 0; o >>= 1) s += __shfl_down(s, o);
    if (lane == 0) out[p * REL + j] = s + rb[j];
  }
}

// --------------------------------------------------------------- launch ----
extern "C" void kernel_launch(void* const* d_in, const int* in_sizes, int n_in,
                              void* d_out, int out_size, void* d_ws, size_t ws_size,
                              hipStream_t stream) {
  const float* inputs = (const float*)d_in[0];
  const float* ner    = (const float*)d_in[1];
  const float* refeat = (const float*)d_in[2];
  const float* adj    = (const float*)d_in[3];
  const float* W0w    = (const float*)d_in[4];
  const float* W0b    = (const float*)d_in[5];
  const float* W1w    = (const float*)d_in[6];
  const float* W1b    = (const float*)d_in[7];
  const float* outw   = (const float*)d_in[8];
  const float* outb   = (const float*)d_in[9];
  const float* nerw   = (const float*)d_in[10];
  const float* nerb   = (const float*)d_in[11];
  const float* rew    = (const float*)d_in[12];
  const float* reb    = (const float*)d_in[13];
  const int*   ps     = (const int*)d_in[14];
  const int*   hs     = (const int*)d_in[15];
  const int*   ts     = (const int*)d_in[16];
  (void)in_sizes; (void)n_in; (void)out_size; (void)ws_size;
  float* outp = (float*)d_out;

  char* ws = (char*)d_ws;
  size_t off = 0;
  u16* adj_bf = (u16*)(ws + off);               // 88,510,464 B
  u16* logits_bf = adj_bf;                      // overlay (adj dead by then)
  off += (size_t)B_ * NP * NP * 2;
  float* rdenom = (float*)(ws + off); off += (size_t)MTOT * 4;
  u16* zp  = (u16*)(ws + off); off += 512;
  u16* w0t = (u16*)(ws + off); off += 512 * 512 * 2;
  u16* w1t = (u16*)(ws + off); off += 512 * 512 * 2;
  u16* owt = (u16*)(ws + off); off += 512 * 1024 * 2;
  u16* xt  = (u16*)(ws + off); off += (size_t)B_ * 512 * NP * 2;  // x0t / g0t
  u16* S   = (u16*)(ws + off); off += (size_t)MTOT * 512 * 2;
  u16* g0  = (u16*)(ws + off); off += (size_t)MTOT * 512 * 2;
  u16* g1  = (u16*)(ws + off); off += (size_t)MTOT * 512 * 2;

  zero_zp<<<1, 256, 0, stream>>>(zp);
  prep_adj<<<MTOT, 256, 0, stream>>>(adj, adj_bf, rdenom);

  dim3 gT((NP + 63) / 64, D_ / 64, B_);         // (37, 8, 8)
  tcvt<<<gT, 256, 0, stream>>>(inputs, xt, NP, D_, (size_t)NP * D_, (size_t)D_ * NP);
  tcvt<<<dim3(8, 8, 1),  256, 0, stream>>>(W0w,  w0t, 512,  512, 0, 0);
  tcvt<<<dim3(8, 8, 1),  256, 0, stream>>>(W1w,  w1t, 512,  512, 0, 0);
  tcvt<<<dim3(16, 8, 1), 256, 0, stream>>>(outw, owt, 1024, 512, 0, 0);

  gemm8<0,0><<<608, 512, 0, stream>>>(adj_bf, nullptr, xt, xt,
                                      nullptr, nullptr, zp, S, nullptr);
  gemm8<1,1><<<588, 512, 0, stream>>>(S, nullptr, w0t, nullptr,
                                      W0b, rdenom, zp, g0, xt);
  gemm8<0,0><<<608, 512, 0, stream>>>(adj_bf, nullptr, xt, xt,
                                      nullptr, nullptr, zp, S, nullptr);
  gemm8<1,0><<<588, 512, 0, stream>>>(S, nullptr, w1t, nullptr,
                                      W1b, rdenom, zp, g1, nullptr);
  gemm8<2,0><<<588, 512, 0, stream>>>(g0, g1, owt, nullptr,
                                      outb, nullptr, zp, logits_bf, nullptr);

  ner_kernel <<<B_ * SENT, 64,  0, stream>>>(ner, logits_bf, nerw, nerb, outp);
  pair_kernel<<<PAIRS,     256, 0, stream>>>(logits_bf, refeat, rew, reb, ps, hs, ts,
                                             outp + B_ * SENT * NERL);
}

// Round 11
// 363.558 us; speedup vs baseline: 1.1819x; 1.1819x over previous
//
#include <hip/hip_runtime.h>
#include <hip/hip_bf16.h>

#define B_    8
#define NP    2352
#define D_    512
#define SENT  48
#define PAIRS 512
#define NERL  16
#define REL   32
#define MTOT  (B_*NP)   // 18816
#define SLOTB 640       // slots per batch (48 ner + up to 148 pairs * 4)
#define MG    (B_*SLOTB) // 5120 gathered slots = 40 tiles of 128

typedef unsigned short u16;
typedef __bf16 bf16x8 __attribute__((ext_vector_type(8)));
typedef float  f32x4  __attribute__((ext_vector_type(4)));

__device__ __forceinline__ u16 f2b(float f) {
  union { float f; unsigned u; } c; c.f = f;
  unsigned u = c.u;
  u += 0x7fffu + ((u >> 16) & 1u);           // round-to-nearest-even
  return (u16)(u >> 16);
}
__device__ __forceinline__ float b2f(u16 h) {
  union { unsigned u; float f; } c; c.u = ((unsigned)h) << 16;
  return c.f;
}
__device__ __forceinline__ void gload16(const u16* g, u16* lds) {
  __builtin_amdgcn_global_load_lds(
      (const __attribute__((address_space(1))) unsigned*)g,
      (__attribute__((address_space(3))) unsigned*)lds, 16, 0, 0);
}

// ----------------------------------------------------------------- zero ----
__global__ void zero_zp(u16* zp) { zp[threadIdx.x] = 0; }

// ------------------------------------------------------------- prep_adj ----
__global__ __launch_bounds__(256) void prep_adj(const float* __restrict__ adj,
                                                u16* __restrict__ adjb,
                                                float* __restrict__ rdenom) {
  const int row = blockIdx.x;                 // 0..18815
  const float4* src = (const float4*)(adj + (size_t)row * NP);
  ushort4* dst = (ushort4*)(adjb + (size_t)row * NP);
  float s = 0.f;
  for (int i = threadIdx.x; i < NP / 4; i += 256) {
    float4 v = src[i];
    s += (v.x + v.y) + (v.z + v.w);
    ushort4 o; o.x = f2b(v.x); o.y = f2b(v.y); o.z = f2b(v.z); o.w = f2b(v.w);
    dst[i] = o;
  }
  #pragma unroll
  for (int o = 32; o > 0; o >>= 1) s += __shfl_down(s, o, 64);
  __shared__ float red[4];
  int w = threadIdx.x >> 6, l = threadIdx.x & 63;
  if (l == 0) red[w] = s;
  __syncthreads();
  if (threadIdx.x == 0)
    rdenom[row] = 1.f / (red[0] + red[1] + red[2] + red[3] + 1.f);
}

// ------------------------------------------------------------- pair_prep ---
// Deterministic slot assignment (rank = #earlier pairs in same batch).
// rowmap[slot] = source row within batch; pslot[p] = first of pair p's 4
// slots; rdenom_g = gathered 1/denom. Unused slots -> row 0 (never read).
__global__ __launch_bounds__(512) void pair_prep(const int* __restrict__ ps,
                                                 const int* __restrict__ hs,
                                                 const int* __restrict__ ts,
                                                 const float* __restrict__ rdenom,
                                                 int* __restrict__ rowmap,
                                                 int* __restrict__ pslot,
                                                 float* __restrict__ rdenom_g) {
  __shared__ int sps[PAIRS];
  const int t = threadIdx.x;
  sps[t] = ps[t];
  for (int i = t; i < MG; i += 512) rowmap[i] = 0;
  __syncthreads();
  if (t < B_ * SENT) {                       // ner slots
    int b = t / SENT, j = t % SENT;
    rowmap[b * SLOTB + j] = j;
  }
  const int b = sps[t];
  int rank = 0;
  for (int q = 0; q < t; ++q) rank += (sps[q] == b) ? 1 : 0;
  const int h = hs[t], tt = ts[t];
  const int s0 = b * SLOTB + SENT + 4 * rank;
  rowmap[s0 + 0] = (h + 1) * SENT + tt;
  rowmap[s0 + 1] = (h + 1) * SENT + tt + 1;
  rowmap[s0 + 2] = (h + 2) * SENT + tt;
  rowmap[s0 + 3] = (h + 2) * SENT + tt + 1;
  pslot[t] = s0;
  __syncthreads();
  for (int i = t; i < MG; i += 512)
    rdenom_g[i] = rdenom[(i / SLOTB) * NP + rowmap[i]];
}

// ----------------------------------------------------- transpose-convert ---
__global__ __launch_bounds__(256) void tcvt(const float* __restrict__ in_,
                                            u16* __restrict__ out,
                                            int R, int C, size_t inb, size_t outb) {
  __shared__ u16 tile[64][65];
  const int b  = blockIdx.z;
  const int r0 = blockIdx.x * 64, c0 = blockIdx.y * 64;
  const int t  = threadIdx.x;
  const int tr = t >> 4, tc = (t & 15) * 4;
  #pragma unroll
  for (int i = 0; i < 4; ++i) {
    int rl = i * 16 + tr;
    int r  = r0 + rl;
    if (r < R) {
      const float* in = in_ + (size_t)b * inb + (size_t)r * C + c0 + tc;
      float4 v = *(const float4*)in;
      tile[rl][tc + 0] = f2b(v.x); tile[rl][tc + 1] = f2b(v.y);
      tile[rl][tc + 2] = f2b(v.z); tile[rl][tc + 3] = f2b(v.w);
    }
  }
  __syncthreads();
  const int c  = t >> 2;
  const int rb = (t & 3) * 16;
  u16* orow = out + (size_t)b * outb + (size_t)(c0 + c) * R + r0;
  #pragma unroll
  for (int i = 0; i < 4; ++i) {
    int rl = rb + i * 4;
    int r  = r0 + rl;
    if (r + 3 < R) {
      ushort4 v;
      v.x = tile[rl + 0][c]; v.y = tile[rl + 1][c];
      v.z = tile[rl + 2][c]; v.w = tile[rl + 3][c];
      *(ushort4*)(orow + rl) = v;
    } else {
      for (int j = 0; j < 4; ++j)
        if (r + j < R) orow[rl + j] = tile[rl + j][c];
    }
  }
}

// ------------------------------------------- 4-wave 128x128 GEMM core ------
// R8 structure (BM=BN=128, BK=64, dbuf-2 = 64 KB LDS, 2 blocks/CU, T3-min
// schedule, both-sides slot swizzle, zero-page K-tail).
// GATHER=1: M = 5120 slots; grid 160 = 8 XCD x 20 (batch per XCD).
//   A-row gather through rowmap applies to MODE 0 (adj rows) and MODE 2's
//   g0 half ONLY — MODE 1's A (S_g) is already slot-major (R10 crash fix:
//   was dereferencing rowmap=nullptr in <1,0,1>).
// MODE 0: S = adj@X^T (+x epi)   MODE 1: (S@W + 2b)*rdenom, relu
// MODE 2: concat(g0,g1)@outw + b  (GATHER: A1 = g0 gathered, A2 slot-major)
template<int MODE, int WRITE_T, int GATHER>
__global__ __launch_bounds__(256, 2) void gemm8(
    const u16* __restrict__ A, const u16* __restrict__ A2,
    const u16* __restrict__ Bm, const u16* __restrict__ Xt,
    const float* __restrict__ bias, const float* __restrict__ rdenom,
    const int* __restrict__ rowmap,
    const u16* __restrict__ zp, u16* __restrict__ out, u16* __restrict__ outT)
{
  constexpr int KACT   = (MODE == 0) ? NP : (MODE == 1 ? 512 : 1024);
  constexpr int KTILES = (KACT + 63) / 64;     // 37 / 8 / 16
  constexpr int LDA    = (MODE == 0) ? NP : 512;
  constexpr int LDB    = KACT;

  int m0, n0, bat = 0;
  const u16* Ab = A;
  const u16* Bb = Bm;
  const u16* Xb = Xt;
  size_t outBase = 0;
  if constexpr (GATHER) {
    // grid 160 = 8 XCDs x 20; rid = xcd*20+pos; 40 m-tiles x 4 n-tiles.
    // mt: 5 per batch (SLOTB=640=5*128) -> XCD c serves exactly batch c.
    const int bx  = blockIdx.x;
    const int rid = (bx & 7) * 20 + (bx >> 3);
    const int mt  = rid >> 2;                 // 0..39
    n0 = (rid & 3) << 7;
    m0 = mt * 128;                            // slot-space
    bat = mt / 5;
    if constexpr (MODE == 0) {
      Ab = A  + (size_t)bat * NP * NP;
      Bb = Bm + (size_t)bat * 512 * NP;
    }
  } else if constexpr (MODE == 0) {
    // grid 608 = 8 XCD chunks x 76 (one batch per chunk); 19 m x 4 n
    const int bx  = blockIdx.x;
    bat = bx & 7;
    const int loc = bx >> 3;                  // 0..75
    const int mt  = loc >> 2;                 // 0..18
    n0 = (loc & 3) << 7;
    m0 = (mt < 18) ? mt * 128 : NP - 128;     // overlap last tile
    Ab = A  + (size_t)bat * NP * NP;
    Bb = Bm + (size_t)bat * 512 * NP;
    Xb = Xt + (size_t)bat * 512 * NP;
    outBase = (size_t)bat * NP * 512;
  } else {
    // grid 588 = 147 m x 4 n; bijective XCD chunking (q=73, r=4)
    const int bx  = blockIdx.x;
    const int xcd = bx & 7, pos = bx >> 3;
    const int rid = (xcd < 4) ? xcd * 74 + pos : 296 + (xcd - 4) * 73 + pos;
    const int mt  = rid >> 2;                 // 0..146
    n0 = (rid & 3) << 7;
    m0 = mt * 128;                            // exact (147*128 = 18816)
  }

  // [dbuf][slab][128 rows][4 slots x 8 u16]; u16 off = d*8192+s*4096+row*32+slot*8
  __shared__ __align__(16) u16 As[2 * 8192];   // 32 KB
  __shared__ __align__(16) u16 Bs[2 * 8192];   // 32 KB

  const int tid = threadIdx.x;
  const int l  = tid & 63;
  const int w  = tid >> 6;
  const int wm = w >> 1, wn = w & 1;
  const int lr = l & 15, lq = l >> 4;

  f32x4 acc[4][4];
  #pragma unroll
  for (int i = 0; i < 4; ++i)
    #pragma unroll
    for (int j = 0; j < 4; ++j)
      acc[i][j] = (f32x4){0.f, 0.f, 0.f, 0.f};

  // Gathered source rows for this thread's 4 staged rows (constant over kt).
  // Gather applies ONLY where A is indexed in original row space:
  // MODE 0 (adj rows) and MODE 2's g0 half. MODE 1's A is slot-major.
  int rsrc[4];
  #pragma unroll
  for (int j = 0; j < 4; ++j) {
    const int row = ((j * 256 + tid) >> 2) & 127;
    if constexpr (GATHER && MODE != 1) rsrc[j] = rowmap[m0 + row];
    else                               rsrc[j] = m0 + row;
  }

  // Stage one operand's full K-tile (both slabs) into dbuf d. 4 loads/thread.
  auto STAGE = [&](int isA, int d, int kt) {
    #pragma unroll
    for (int j = 0; j < 4; ++j) {
      const int cl   = j * 256 + tid;          // 0..1023
      const int s    = cl >> 9;
      const int row  = (cl >> 2) & 127;
      const int slot = cl & 3;
      const int gch  = kt * 8 + s * 4 + (slot ^ ((row >> 1) & 3));
      const u16* src;
      if (isA) {
        if constexpr (MODE == 2) {
          if constexpr (GATHER) {
            src = (gch < 64)
                ? A  + ((size_t)bat * NP + rsrc[j]) * 512 + gch * 8
                : A2 + (size_t)(m0 + row) * 512 + (gch - 64) * 8;
          } else {
            src = (gch < 64) ? A  + (size_t)(m0 + row) * 512 + gch * 8
                             : A2 + (size_t)(m0 + row) * 512 + (gch - 64) * 8;
          }
        } else {
          src = Ab + (size_t)rsrc[j] * LDA + gch * 8;
        }
        if (gch * 8 + 8 > KACT) src = zp;
        gload16(src, As + d * 8192 + cl * 8);
      } else {
        src = Bb + (size_t)(n0 + row) * LDB + gch * 8;
        if (gch * 8 + 8 > KACT) src = zp;
        gload16(src, Bs + d * 8192 + cl * 8);
      }
    }
  };

  // prologue: tile 0 into buf 0
  STAGE(1, 0, 0);
  STAGE(0, 0, 0);
  asm volatile("s_waitcnt vmcnt(0)" ::: "memory");
  __builtin_amdgcn_s_barrier();

  int d = 0;
  for (int kt = 0; kt < KTILES; ++kt) {
    if (kt + 1 < KTILES) {
      STAGE(1, d ^ 1, kt + 1);
      STAGE(0, d ^ 1, kt + 1);
    }
    const u16* Ad = As + d * 8192;
    const u16* Bd = Bs + d * 8192;
    bf16x8 a0[4], b0[4], a1[4], b1[4];
    #pragma unroll
    for (int f = 0; f < 4; ++f) {
      const int ra = wm * 64 + f * 16 + lr;
      const int rb = wn * 64 + f * 16 + lr;
      const int sa = (lq ^ ((ra >> 1) & 3)) << 3;
      const int sb = (lq ^ ((rb >> 1) & 3)) << 3;
      a0[f] = *(const bf16x8*)(Ad + ra * 32 + sa);
      b0[f] = *(const bf16x8*)(Bd + rb * 32 + sb);
      a1[f] = *(const bf16x8*)(Ad + 4096 + ra * 32 + sa);
      b1[f] = *(const bf16x8*)(Bd + 4096 + rb * 32 + sb);
    }
    asm volatile("s_waitcnt lgkmcnt(0)" ::: "memory");
    __builtin_amdgcn_sched_barrier(0);          // rule #18
    __builtin_amdgcn_s_setprio(1);
    #pragma unroll
    for (int mf = 0; mf < 4; ++mf)
      #pragma unroll
      for (int nf = 0; nf < 4; ++nf)
        acc[mf][nf] = __builtin_amdgcn_mfma_f32_16x16x32_bf16(
            a0[mf], b0[nf], acc[mf][nf], 0, 0, 0);
    #pragma unroll
    for (int mf = 0; mf < 4; ++mf)
      #pragma unroll
      for (int nf = 0; nf < 4; ++nf)
        acc[mf][nf] = __builtin_amdgcn_mfma_f32_16x16x32_bf16(
            a1[mf], b1[nf], acc[mf][nf], 0, 0, 0);
    __builtin_amdgcn_s_setprio(0);
    __builtin_amdgcn_sched_barrier(0);
    asm volatile("s_waitcnt vmcnt(0)" ::: "memory");  // next tile landed
    __builtin_amdgcn_s_barrier();
    d ^= 1;
  }

  // --------------------------------------------------------- epilogue ----
  #pragma unroll
  for (int mf = 0; mf < 4; ++mf) {
    const int gm0 = m0 + wm * 64 + mf * 16 + lq * 4;
    f32x4 rd;
    if constexpr (MODE == 1) rd = *(const f32x4*)(rdenom + gm0);
    int rsm[4];
    if constexpr (GATHER && MODE == 0) {
      #pragma unroll
      for (int r = 0; r < 4; ++r) rsm[r] = rowmap[gm0 + r];
    }
    #pragma unroll
    for (int nf = 0; nf < 4; ++nf) {
      const int gn = n0 + wn * 64 + nf * 16 + lr;
      u16 ov[4];
      if constexpr (MODE == 0) {
        float xf[4];
        if constexpr (GATHER) {
          // Xt = g0 row-major [MTOT][512]; lanes read consecutive gn.
          #pragma unroll
          for (int r = 0; r < 4; ++r)
            xf[r] = b2f(Xt[((size_t)bat * NP + rsm[r]) * 512 + gn]);
        } else {
          ushort4 xv = *(const ushort4*)(Xb + (size_t)gn * NP + gm0);
          xf[0] = b2f(xv.x); xf[1] = b2f(xv.y);
          xf[2] = b2f(xv.z); xf[3] = b2f(xv.w);
        }
        #pragma unroll
        for (int r = 0; r < 4; ++r) ov[r] = f2b(acc[mf][nf][r] + xf[r]);
      } else if constexpr (MODE == 1) {
        const float bn = 2.f * bias[gn];
        #pragma unroll
        for (int r = 0; r < 4; ++r)
          ov[r] = f2b(fmaxf((acc[mf][nf][r] + bn) * rd[r], 0.f));
      } else {
        const float bn = bias[gn];
        #pragma unroll
        for (int r = 0; r < 4; ++r) ov[r] = f2b(acc[mf][nf][r] + bn);
      }
      #pragma unroll
      for (int r = 0; r < 4; ++r)
        out[outBase + (size_t)(gm0 + r) * 512 + gn] = ov[r];
      if constexpr (WRITE_T) {
        const int bb = gm0 / NP;                 // quad never straddles batch
        const int ml = gm0 - bb * NP;
        ushort4 tv; tv.x = ov[0]; tv.y = ov[1]; tv.z = ov[2]; tv.w = ov[3];
        *(ushort4*)(outT + ((size_t)bb * 512 + gn) * NP + ml) = tv;
      }
    }
  }
}

// ------------------------------------------------------------- ner head ----
__global__ __launch_bounds__(64) void ner_kernel(const float* __restrict__ ner,
                                                 const u16* __restrict__ logits_g,
                                                 const float* __restrict__ nw,
                                                 const float* __restrict__ nb,
                                                 float* __restrict__ out) {
  int r = blockIdx.x;                 // 0..383
  int b = r / SENT, tp = r % SENT;
  int lane = threadIdx.x;
  const float* nrow = ner      + ((size_t)b * SENT  + tp) * D_;
  const u16*   lrow = logits_g + ((size_t)b * SLOTB + tp) * D_;
  float rv[16];
  #pragma unroll
  for (int i = 0; i < 8; ++i) rv[i]     = nrow[lane + i * 64];
  #pragma unroll
  for (int i = 0; i < 8; ++i) rv[8 + i] = b2f(lrow[lane + i * 64]);
  for (int j = 0; j < NERL; ++j) {
    float s = 0.f;
    #pragma unroll
    for (int i = 0; i < 16; ++i)
      s = fmaf(rv[i], nw[(size_t)(lane + i * 64) * NERL + j], s);
    for (int o = 32; o > 0; o >>= 1) s += __shfl_down(s, o);
    if (lane == 0) out[r * NERL + j] = s + nb[j];
  }
}

// ----------------------------------------------------------- pair + re -----
__global__ __launch_bounds__(256) void pair_kernel(const u16* __restrict__ logits_g,
                                                   const float* __restrict__ refeat,
                                                   const float* __restrict__ rw,
                                                   const float* __restrict__ rb,
                                                   const int* __restrict__ pslot,
                                                   float* __restrict__ out) {
  int p = blockIdx.x;
  __shared__ float avg[D_];
  const u16* r0 = logits_g + (size_t)pslot[p] * D_;   // 4 consecutive slots
  for (int dd = threadIdx.x; dd < D_; dd += 256)
    avg[dd] = 0.25f * (b2f(r0[dd]) + b2f(r0[D_ + dd]) +
                       b2f(r0[2 * D_ + dd]) + b2f(r0[3 * D_ + dd]));
  __syncthreads();
  int wave = threadIdx.x >> 6, lane = threadIdx.x & 63;
  const float* rf = refeat + (size_t)p * D_;
  for (int jj = 0; jj < 8; ++jj) {
    int j = wave * 8 + jj;
    float s = 0.f;
    #pragma unroll
    for (int i = 0; i < 8; ++i) {
      int k = lane + i * 64;
      s = fmaf(rf[k],  rw[(size_t)k * REL + j], s);
      s = fmaf(avg[k], rw[(size_t)(k + D_) * REL + j], s);
    }
    for (int o = 32; o > 0; o >>= 1) s += __shfl_down(s, o);
    if (lane == 0) out[p * REL + j] = s + rb[j];
  }
}

// --------------------------------------------------------------- launch ----
extern "C" void kernel_launch(void* const* d_in, const int* in_sizes, int n_in,
                              void* d_out, int out_size, void* d_ws, size_t ws_size,
                              hipStream_t stream) {
  const float* inputs = (const float*)d_in[0];
  const float* ner    = (const float*)d_in[1];
  const float* refeat = (const float*)d_in[2];
  const float* adj    = (const float*)d_in[3];
  const float* W0w    = (const float*)d_in[4];
  const float* W0b    = (const float*)d_in[5];
  const float* W1w    = (const float*)d_in[6];
  const float* W1b    = (const float*)d_in[7];
  const float* outw   = (const float*)d_in[8];
  const float* outb   = (const float*)d_in[9];
  const float* nerw   = (const float*)d_in[10];
  const float* nerb   = (const float*)d_in[11];
  const float* rew    = (const float*)d_in[12];
  const float* reb    = (const float*)d_in[13];
  const int*   ps     = (const int*)d_in[14];
  const int*   hs     = (const int*)d_in[15];
  const int*   ts     = (const int*)d_in[16];
  (void)in_sizes; (void)n_in; (void)out_size; (void)ws_size;
  float* outp = (float*)d_out;

  char* ws = (char*)d_ws;
  size_t off = 0;
  u16* adj_bf = (u16*)(ws + off); off += (size_t)B_ * NP * NP * 2;  // 88.5 MB
  float* rdenom = (float*)(ws + off); off += (size_t)MTOT * 4;
  u16* zp  = (u16*)(ws + off); off += 512;
  u16* w0t = (u16*)(ws + off); off += 512 * 512 * 2;
  u16* w1t = (u16*)(ws + off); off += 512 * 512 * 2;
  u16* owt = (u16*)(ws + off); off += 512 * 1024 * 2;
  u16* xt  = (u16*)(ws + off); off += (size_t)B_ * 512 * NP * 2;   // x0t / g0t
  u16* S   = (u16*)(ws + off); off += (size_t)MTOT * 512 * 2;
  u16* g0  = (u16*)(ws + off); off += (size_t)MTOT * 512 * 2;
  int* rowmap = (int*)(ws + off); off += (size_t)MG * 4;
  int* pslot  = (int*)(ws + off); off += (size_t)PAIRS * 4;
  float* rdenom_g = (float*)(ws + off); off += (size_t)MG * 4;
  u16* S_g      = (u16*)(ws + off); off += (size_t)MG * 512 * 2;
  u16* g1_g     = (u16*)(ws + off); off += (size_t)MG * 512 * 2;
  u16* logits_g = (u16*)(ws + off); off += (size_t)MG * 512 * 2;

  zero_zp<<<1, 256, 0, stream>>>(zp);
  prep_adj<<<MTOT, 256, 0, stream>>>(adj, adj_bf, rdenom);
  pair_prep<<<1, 512, 0, stream>>>(ps, hs, ts, rdenom, rowmap, pslot, rdenom_g);

  dim3 gT((NP + 63) / 64, D_ / 64, B_);         // (37, 8, 8)
  tcvt<<<gT, 256, 0, stream>>>(inputs, xt, NP, D_, (size_t)NP * D_, (size_t)D_ * NP);
  tcvt<<<dim3(8, 8, 1),  256, 0, stream>>>(W0w,  w0t, 512,  512, 0, 0);
  tcvt<<<dim3(8, 8, 1),  256, 0, stream>>>(W1w,  w1t, 512,  512, 0, 0);
  tcvt<<<dim3(16, 8, 1), 256, 0, stream>>>(outw, owt, 1024, 512, 0, 0);

  // Layer 1 (full): S = adj@x + x ; g0 = relu((S@W0 + 2b)/denom) (+g0^T)
  gemm8<0,0,0><<<608, 256, 0, stream>>>(adj_bf, nullptr, xt, xt,
                                        nullptr, nullptr, nullptr, zp, S, nullptr);
  gemm8<1,1,0><<<588, 256, 0, stream>>>(S, nullptr, w0t, nullptr,
                                        W0b, rdenom, nullptr, zp, g0, xt);
  // Layer 2 (gathered, M = 5120 slots)
  gemm8<0,0,1><<<160, 256, 0, stream>>>(adj_bf, nullptr, xt, g0,
                                        nullptr, nullptr, rowmap, zp, S_g, nullptr);
  gemm8<1,0,1><<<160, 256, 0, stream>>>(S_g, nullptr, w1t, nullptr,
                                        W1b, rdenom_g, rowmap, zp, g1_g, nullptr);
  gemm8<2,0,1><<<160, 256, 0, stream>>>(g0, g1_g, owt, nullptr,
                                        outb, nullptr, rowmap, zp, logits_g, nullptr);

  ner_kernel <<<B_ * SENT, 64,  0, stream>>>(ner, logits_g, nerw, nerb, outp);
  pair_kernel<<<PAIRS,     256, 0, stream>>>(logits_g, refeat, rew, reb, pslot,
                                             outp + B_ * SENT * NERL);
}